// Round 18
// baseline (28.731 us; speedup 1.0000x reference)
//
#include <hip/hip_runtime.h>
#include <math.h>

// B=4, N=16, K=16, H=64, O=1.  W: (a,b,d,e,k,o) fp32 = 256 MiB.
// h[z,a,o] = sum_j P[z,a,j] W[a,j,o];  P = <basis(a,b,k),basis(d,e,k)>_z
// out[z,a] = silu(h[z,a,:]) . w_fc + b_fc
//
// Cosine cutoff (dist>=5) + zero diagonal kill ~73% of W rows exactly ->
// skipped bit-exactly via ballot-derived group masks.
// R18 = R17 (28.2us) + two k_main-internal fixes:
//  1. BLOCK-WIDE group mask, waves take groups round-robin (idx%4==wave):
//     per-wave iterations = ceil(total/4) instead of max-per-wave-span.
//  2. PAIR-LEVEL LDS staging: 132 threads compute per-(pair,z) invariants
//     {diff, cut/nsq, exp(-nrm)} once; per-thread work drops to
//     3 exps + 2 raw dot3s per z (su*sv*(du.dv) refactor, ~1ulp reorder).
//
// ws (floats): part : [16][128][256] = 524,288 f @ 0   (2 MB)

#define NJ 65536
#define BPA 128   // blocks per 'a' -> 2048 blocks

typedef float f32x4 __attribute__((ext_vector_type(4)));
typedef unsigned int u32;

static constexpr double D_START = 0.006737946999085467; // exp(-5)

#define ACC8(pA, pB, wA, wB) do {                                              \
    acc[0][0] += pA.x * wA.x + pB.x * wB.x; acc[0][1] += pA.x * wA.y + pB.x * wB.y; \
    acc[0][2] += pA.x * wA.z + pB.x * wB.z; acc[0][3] += pA.x * wA.w + pB.x * wB.w; \
    acc[1][0] += pA.y * wA.x + pB.y * wB.x; acc[1][1] += pA.y * wA.y + pB.y * wB.y; \
    acc[1][2] += pA.y * wA.z + pB.y * wB.z; acc[1][3] += pA.y * wA.w + pB.y * wB.w; \
    acc[2][0] += pA.z * wA.x + pB.z * wB.x; acc[2][1] += pA.z * wA.y + pB.z * wB.y; \
    acc[2][2] += pA.z * wA.z + pB.z * wB.z; acc[2][3] += pA.z * wA.w + pB.z * wB.w; \
    acc[3][0] += pA.w * wA.x + pB.w * wB.x; acc[3][1] += pA.w * wA.y + pB.w * wB.y; \
    acc[3][2] += pA.w * wA.z + pB.w * wB.z; acc[3][3] += pA.w * wA.w + pB.w * wB.w; \
} while (0)

__global__ __launch_bounds__(256) void k_main(const f32x4* __restrict__ W4,
                                              const float* __restrict__ x,
                                              float* __restrict__ part) {
    int a   = blockIdx.x >> 7;        // sequential mapping (best measured)
    int blk = blockIdx.x & (BPA - 1); // (b, d-pair)
    int b  = blk >> 3, dd = (blk & 7) * 2;

    __shared__ f32x4 p_lds[512];
    __shared__ float red[4][256];
    __shared__ float s_d0[132], s_d1[132], s_d2[132], s_cc[132], s_ex[132];
    __shared__ u32 s_gm[4];

    const float START = (float)D_START;
    const float STEP  = (float)((1.0 - D_START) / 15.0);
    const float BETA  = (float)(1.0 / ((0.125 * (1.0 - D_START)) * (0.125 * (1.0 - D_START))));

    int t = threadIdx.x;

    // ---- stage pair-level invariants: 33 pairs x 4 z ----
    // pr==0: (a,b); pr 1..16: (dd, e=pr-1); pr 17..32: (dd+1, e=pr-17)
    if (t < 132) {
        int z = t / 33, pr = t - z * 33;
        int p, q;
        if (pr == 0)      { p = a;      q = b; }
        else if (pr < 17) { p = dd;     q = pr - 1; }
        else              { p = dd + 1; q = pr - 17; }
        const float* xp = x + (z * 16 + p) * 3;
        const float* xq = x + (z * 16 + q) * 3;
        float d0 = xp[0] - xq[0], d1 = xp[1] - xq[1], d2 = xp[2] - xq[2];
        float nsq = d0 * d0 + d1 * d1 + d2 * d2 + 1e-5f;
        float nrm = sqrtf(nsq);
        float cc = 0.f, ex = 0.f;
        if (nrm < 5.0f) {
            cc = 0.5f * (cosf(nrm * 0.6283185307179586f) + 1.0f) / nsq;
            ex = expf(-nrm);
        }
        s_d0[t] = d0; s_d1[t] = d1; s_d2[t] = d2; s_cc[t] = cc; s_ex[t] = ex;
    }
    __syncthreads();

    // ---- per-thread P for rows t (d=dd) and t+256 (d=dd+1) ----
    int e = t >> 4, k = t & 15;
    float mk = START + STEP * (float)k;
    f32x4 p0, p1;
    #pragma unroll
    for (int z = 0; z < 4; ++z) {
        int base = z * 33;
        float exu = s_ex[base];
        float su  = s_cc[base] * expf(-BETA * (exu - mk) * (exu - mk));
        float du0 = s_d0[base], du1 = s_d1[base], du2 = s_d2[base];
        int i0 = base + 1 + e;
        float exv0 = s_ex[i0];
        float sv0  = s_cc[i0] * expf(-BETA * (exv0 - mk) * (exv0 - mk));
        float dot0 = du0 * s_d0[i0] + du1 * s_d1[i0] + du2 * s_d2[i0];
        p0[z] = su * sv0 * dot0;
        int i1 = base + 17 + e;
        float exv1 = s_ex[i1];
        float sv1  = s_cc[i1] * expf(-BETA * (exv1 - mk) * (exv1 - mk));
        float dot1 = du0 * s_d0[i1] + du1 * s_d1[i1] + du2 * s_d2[i1];
        p1[z] = su * sv1 * dot1;
    }
    bool f0 = (fabsf(p0.x) + fabsf(p0.y) + fabsf(p0.z) + fabsf(p0.w)) != 0.0f;
    bool f1 = (fabsf(p1.x) + fabsf(p1.y) + fabsf(p1.z) + fabsf(p1.w)) != 0.0f;
    unsigned long long bal0 = __ballot(f0);  // rows [w*64, w*64+64)
    unsigned long long bal1 = __ballot(f1);  // rows [256+w*64, ...)
    p_lds[t]       = p0;
    p_lds[t + 256] = p1;

    int wave = t >> 6;
    int lane = t & 63;
    int og   = lane & 15;  // group of 4 'o' columns
    int rsub = lane >> 4;  // row within the 4-row group

    // per-wave e-level masks -> block-wide 64-bit group mask (g -> rloc=8g)
    u32 m0 = 0, m1 = 0;
    #pragma unroll
    for (int i = 0; i < 4; ++i) {
        if ((bal0 >> (16 * i)) & 0xFFFFull) m0 |= 3u << (2 * i);
        if ((bal1 >> (16 * i)) & 0xFFFFull) m1 |= 3u << (2 * i);
    }
    if (lane == 0) s_gm[wave] = m0 | (m1 << 8);
    __syncthreads();
    unsigned long long m64 = 0;
    #pragma unroll
    for (int i = 0; i < 4; ++i) {
        u32 v = s_gm[i];
        m64 |= (unsigned long long)(v & 0xFFu) << (8 * i);
        m64 |= (unsigned long long)((v >> 8) & 0xFFu) << (32 + 8 * i);
    }

    float acc[4][4] = {{0.f, 0.f, 0.f, 0.f}, {0.f, 0.f, 0.f, 0.f},
                       {0.f, 0.f, 0.f, 0.f}, {0.f, 0.f, 0.f, 0.f}};
    size_t rowbase = (size_t)a * NJ + (size_t)blk * 512;
    // ---- balanced pipelined skip loop: wave takes groups idx%4==wave ----
    {
        int idx = 0;
        bool have = false;
        f32x4 pAp, pBp, wAp, wBp;
        while (m64) {
            int g = __builtin_ctzll(m64);
            m64 &= m64 - 1;
            if ((idx++ & 3) != wave) continue;
            int rloc = g * 8 + rsub;
            f32x4 pA = p_lds[rloc];
            f32x4 pB = p_lds[rloc + 4];
            f32x4 wA = W4[(rowbase + rloc) * 16 + og];       // 1 KB/wave
            f32x4 wB = W4[(rowbase + rloc + 4) * 16 + og];   // 1 KB/wave
            if (have) ACC8(pAp, pBp, wAp, wBp);              // prev, vmcnt(2)
            pAp = pA; pBp = pB; wAp = wA; wBp = wB; have = true;
        }
        if (have) ACC8(pAp, pBp, wAp, wBp);
    }

    // reduce across the 4 row-subgroups (lane bits 4,5)
    #pragma unroll
    for (int z = 0; z < 4; ++z) {
        #pragma unroll
        for (int c = 0; c < 4; ++c) {
            float v = acc[z][c];
            v += __shfl_xor(v, 16);
            v += __shfl_xor(v, 32);
            acc[z][c] = v;
        }
    }
    if (rsub == 0) {
        #pragma unroll
        for (int z = 0; z < 4; ++z) {
            #pragma unroll
            for (int c = 0; c < 4; ++c)
                red[wave][z * 64 + og * 4 + c] = acc[z][c];
        }
    }
    __syncthreads();
    // (z*64 + o) = t
    float s = red[0][t] + red[1][t] + red[2][t] + red[3][t];
    part[((size_t)a * BPA + blk) * 256 + t] = s;
}

__global__ void k_out(const float* __restrict__ part, const float* __restrict__ w_fc,
                      const float* __restrict__ b_fc, float* __restrict__ out) {
    // one block per (z,a); 256 threads = 4 blk-quarters x 64 'o'
    int z = blockIdx.x >> 4, a = blockIdx.x & 15;
    int o = threadIdx.x & 63, bq = threadIdx.x >> 6;
    float s = 0.f;
    for (int blk = bq; blk < BPA; blk += 4)
        s += part[((size_t)a * BPA + blk) * 256 + z * 64 + o]; // coalesced over o
    __shared__ float red[4][64];
    red[bq][o] = s;
    __syncthreads();
    if (threadIdx.x < 64) {
        float h = red[0][o] + red[1][o] + red[2][o] + red[3][o];
        float v = h * (1.0f / (1.0f + expf(-h))) * w_fc[o]; // silu * weight
        #pragma unroll
        for (int off = 32; off >= 1; off >>= 1) v += __shfl_xor(v, off);
        if (o == 0) out[z * 16 + a] = v + b_fc[0];
    }
}

extern "C" void kernel_launch(void* const* d_in, const int* in_sizes, int n_in,
                              void* d_out, int out_size, void* d_ws, size_t ws_size,
                              hipStream_t stream) {
    const float* x    = (const float*)d_in[0];
    const float* W    = (const float*)d_in[1];
    const float* w_fc = (const float*)d_in[2];
    const float* b_fc = (const float*)d_in[3];
    float* ws  = (float*)d_ws;
    float* out = (float*)d_out;

    float* part = ws;                 // 524,288 floats

    k_main<<<16 * BPA, 256, 0, stream>>>((const f32x4*)W, x, part);
    k_out<<<64, 256, 0, stream>>>(part, w_fc, b_fc, out);
}

// Round 19
// 28.713 us; speedup vs baseline: 1.0006x; 1.0006x over previous
//
#include <hip/hip_runtime.h>
#include <math.h>

// B=4, N=16, K=16, H=64, O=1.  W: (a,b,d,e,k,o) fp32 = 256 MiB.
// h[z,a,o] = sum_j P[z,a,j] W[a,j,o];  P = <basis(a,b,k),basis(d,e,k)>_z
// out[z,a] = silu(h[z,a,:]) . w_fc + b_fc
//
// Cosine cutoff (dist>=5) + zero diagonal kill ~73% of W rows exactly ->
// their loads are skipped (bit-exact, ballot-derived wave-uniform mask).
// R19 = R17 body (best, 28.2us) + LOW-7-BIT XOR SWIZZLE of the block->item
// map: HW gives CU c the 8 blocks {c+256k}; un-swizzled they share
// bi&255 -> the SAME (b,d) pair -> correlated work -> hot-CU tail.
// swz = bi ^ (((bi>>8)*37) & 127) assigns those 8 blocks 8 different
// (b,d) codes while keeping intra-run adjacency (W page locality) and
// bijectivity (bit-exact coverage).
//
// ws (floats): part : [16][128][256] = 524,288 f @ 0   (2 MB)

#define NJ 65536
#define BPA 128   // blocks per 'a' -> 2048 blocks

typedef float f32x4 __attribute__((ext_vector_type(4)));

static constexpr double D_START = 0.006737946999085467; // exp(-5)

#define ACC8(pA, pB, wA, wB) do {                                              \
    acc[0][0] += pA.x * wA.x + pB.x * wB.x; acc[0][1] += pA.x * wA.y + pB.x * wB.y; \
    acc[0][2] += pA.x * wA.z + pB.x * wB.z; acc[0][3] += pA.x * wA.w + pB.x * wB.w; \
    acc[1][0] += pA.y * wA.x + pB.y * wB.x; acc[1][1] += pA.y * wA.y + pB.y * wB.y; \
    acc[1][2] += pA.y * wA.z + pB.y * wB.z; acc[1][3] += pA.y * wA.w + pB.y * wB.w; \
    acc[2][0] += pA.z * wA.x + pB.z * wB.x; acc[2][1] += pA.z * wA.y + pB.z * wB.y; \
    acc[2][2] += pA.z * wA.z + pB.z * wB.z; acc[2][3] += pA.z * wA.w + pB.z * wB.w; \
    acc[3][0] += pA.w * wA.x + pB.w * wB.x; acc[3][1] += pA.w * wA.y + pB.w * wB.y; \
    acc[3][2] += pA.w * wA.z + pB.w * wB.z; acc[3][3] += pA.w * wA.w + pB.w * wB.w; \
} while (0)

// basis vector (smear_k * diff / nsq) for pair (p,q) in batch z, rbf k.
__device__ __forceinline__ bool pair_basis(const float* __restrict__ x,
                                           int z, int p, int q, int k,
                                           float& bx, float& by, float& bz) {
    const float* xp = x + (z * 16 + p) * 3;
    const float* xq = x + (z * 16 + q) * 3;
    float d0 = xp[0] - xq[0], d1 = xp[1] - xq[1], d2 = xp[2] - xq[2];
    float nsq = d0 * d0 + d1 * d1 + d2 * d2 + 1e-5f;
    float nrm = sqrtf(nsq);
    if (nrm >= 5.0f) return false;                 // cut == 0 -> basis == 0
    float cut = 0.5f * (cosf(nrm * 0.6283185307179586f) + 1.0f);
    float ex = expf(-nrm); // alpha=1, CUT_LO=0
    const float START = (float)D_START;
    const float STEP  = (float)((1.0 - D_START) / 15.0);
    const float BETA  = (float)(1.0 / ((0.125 * (1.0 - D_START)) * (0.125 * (1.0 - D_START))));
    float m = START + STEP * (float)k;
    float dmm = ex - m;
    float s = cut * expf(-BETA * dmm * dmm) / nsq; // fold /nsq of diff into smear
    bx = s * d0; by = s * d1; bz = s * d2;
    return true;
}

__global__ __launch_bounds__(256) void k_main(const f32x4* __restrict__ W4,
                                              const float* __restrict__ x,
                                              float* __restrict__ part) {
    // decorrelating, locality-preserving bijection (low 7 bits only)
    unsigned swz = blockIdx.x ^ (((blockIdx.x >> 8) * 37u) & 127u);
    int a   = (int)(swz >> 7);
    int blk = (int)(swz & (BPA - 1)); // (b, d-pair)

    __shared__ f32x4 p_lds[512];
    __shared__ float red[4][256];

    // ---- prologue: P for this block's 512 j-rows (j = blk*512 + rloc) ----
    int t = threadIdx.x;
    f32x4 p0 = {0.f, 0.f, 0.f, 0.f}, p1 = {0.f, 0.f, 0.f, 0.f};
    {
        int e = t >> 4, k = t & 15;
        int b = blk >> 3, dd = (blk & 7) * 2;
        #pragma unroll
        for (int z = 0; z < 4; ++z) {
            float ux, uy, uz;
            if (pair_basis(x, z, a, b, k, ux, uy, uz)) { // block-uniform branch
                float vx, vy, vz;
                if (pair_basis(x, z, dd, e, k, vx, vy, vz))
                    p0[z] = ux * vx + uy * vy + uz * vz;
                if (pair_basis(x, z, dd + 1, e, k, vx, vy, vz))
                    p1[z] = ux * vx + uy * vy + uz * vz;
            }
        }
    }
    bool f0 = (fabsf(p0.x) + fabsf(p0.y) + fabsf(p0.z) + fabsf(p0.w)) != 0.0f;
    bool f1 = (fabsf(p1.x) + fabsf(p1.y) + fabsf(p1.z) + fabsf(p1.w)) != 0.0f;
    unsigned long long bal0 = __ballot(f0);  // rows [w*64, w*64+64)
    unsigned long long bal1 = __ballot(f1);  // rows [256+w*64, ...)
    p_lds[t]       = p0;
    p_lds[t + 256] = p1;
    __syncthreads();

    int wave = t >> 6;
    int lane = t & 63;
    int og   = lane & 15;  // group of 4 'o' columns
    int rsub = lane >> 4;  // row within the 4-row group

    // group mask: bits 0..7 = A-half groups, 8..15 = B-half groups
    unsigned mask = 0;
    #pragma unroll
    for (int g = 0; g < 8; ++g) {
        if ((bal0 >> (8 * g)) & 0xFFull) mask |= 1u << g;
        if ((bal1 >> (8 * g)) & 0xFFull) mask |= 1u << (g + 8);
    }

    float acc[4][4] = {{0.f, 0.f, 0.f, 0.f}, {0.f, 0.f, 0.f, 0.f},
                       {0.f, 0.f, 0.f, 0.f}, {0.f, 0.f, 0.f, 0.f}};
    size_t rowbase = (size_t)a * NJ + (size_t)blk * 512;
    // ---- 2-group-per-iter pipelined skip loop (4 KB in flight) ----
    while (mask) {  // wave-uniform: mask derived from ballots
        int g1 = __builtin_ctz(mask);
        mask &= mask - 1;
        int rloc1 = ((g1 & 8) ? 256 : 0) + wave * 64 + (g1 & 7) * 8 + rsub;
        f32x4 pA1 = p_lds[rloc1];
        f32x4 pB1 = p_lds[rloc1 + 4];
        f32x4 wA1 = W4[(rowbase + rloc1) * 16 + og];
        f32x4 wB1 = W4[(rowbase + rloc1 + 4) * 16 + og];
        if (mask) {
            int g2 = __builtin_ctz(mask);
            mask &= mask - 1;
            int rloc2 = ((g2 & 8) ? 256 : 0) + wave * 64 + (g2 & 7) * 8 + rsub;
            f32x4 pA2 = p_lds[rloc2];
            f32x4 pB2 = p_lds[rloc2 + 4];
            f32x4 wA2 = W4[(rowbase + rloc2) * 16 + og];   // in flight
            f32x4 wB2 = W4[(rowbase + rloc2 + 4) * 16 + og];
            ACC8(pA1, pB1, wA1, wB1);                      // waits vmcnt(2)
            ACC8(pA2, pB2, wA2, wB2);
        } else {
            ACC8(pA1, pB1, wA1, wB1);
        }
    }

    // reduce across the 4 row-subgroups (lane bits 4,5)
    #pragma unroll
    for (int z = 0; z < 4; ++z) {
        #pragma unroll
        for (int c = 0; c < 4; ++c) {
            float v = acc[z][c];
            v += __shfl_xor(v, 16);
            v += __shfl_xor(v, 32);
            acc[z][c] = v;
        }
    }
    if (rsub == 0) {
        #pragma unroll
        for (int z = 0; z < 4; ++z) {
            #pragma unroll
            for (int c = 0; c < 4; ++c)
                red[wave][z * 64 + og * 4 + c] = acc[z][c];
        }
    }
    __syncthreads();
    // (z*64 + o) = t
    float s = red[0][t] + red[1][t] + red[2][t] + red[3][t];
    part[((size_t)a * BPA + blk) * 256 + t] = s;
}

__global__ void k_out(const float* __restrict__ part, const float* __restrict__ w_fc,
                      const float* __restrict__ b_fc, float* __restrict__ out) {
    // one block per (z,a); 256 threads = 4 blk-quarters x 64 'o'
    int z = blockIdx.x >> 4, a = blockIdx.x & 15;
    int o = threadIdx.x & 63, bq = threadIdx.x >> 6;
    float s = 0.f;
    for (int blk = bq; blk < BPA; blk += 4)
        s += part[((size_t)a * BPA + blk) * 256 + z * 64 + o]; // coalesced over o
    __shared__ float red[4][64];
    red[bq][o] = s;
    __syncthreads();
    if (threadIdx.x < 64) {
        float h = red[0][o] + red[1][o] + red[2][o] + red[3][o];
        float v = h * (1.0f / (1.0f + expf(-h))) * w_fc[o]; // silu * weight
        #pragma unroll
        for (int off = 32; off >= 1; off >>= 1) v += __shfl_xor(v, off);
        if (o == 0) out[z * 16 + a] = v + b_fc[0];
    }
}

extern "C" void kernel_launch(void* const* d_in, const int* in_sizes, int n_in,
                              void* d_out, int out_size, void* d_ws, size_t ws_size,
                              hipStream_t stream) {
    const float* x    = (const float*)d_in[0];
    const float* W    = (const float*)d_in[1];
    const float* w_fc = (const float*)d_in[2];
    const float* b_fc = (const float*)d_in[3];
    float* ws  = (float*)d_ws;
    float* out = (float*)d_out;

    float* part = ws;                 // 524,288 floats

    k_main<<<16 * BPA, 256, 0, stream>>>((const f32x4*)W, x, part);
    k_out<<<64, 256, 0, stream>>>(part, w_fc, b_fc, out);
}